// Round 4
// baseline (263.102 us; speedup 1.0000x reference)
//
#include <hip/hip_runtime.h>

#define DM 1024
#define NH 16
#define TT 2048
#define BB 2
#define NTOK (BB*TT)
#define DQKV 3072

typedef __attribute__((ext_vector_type(8))) short bf16x8;   // 8 bf16 (4 VGPRs)
typedef __attribute__((ext_vector_type(4))) float f32x4;    // MFMA C/D
typedef __attribute__((ext_vector_type(4))) int  int4v;     // 16B chunk

static __device__ __forceinline__ short f2b(float f) {
  union { float f; unsigned u; } v; v.f = f;
  unsigned r = v.u + 0x7FFFu + ((v.u >> 16) & 1u);   // RNE fp32->bf16
  return (short)(r >> 16);
}

// ---------------- fp32 -> bf16 convert (x) ----------------
__global__ __launch_bounds__(256) void k_convert(const float* __restrict__ in,
                                                 short* __restrict__ out, int n) {
  int i = (blockIdx.x * 256 + threadIdx.x) * 8;
  if (i >= n) return;
  float4 a = *(const float4*)(in + i);
  float4 b = *(const float4*)(in + i + 4);
  bf16x8 o;
  o[0]=f2b(a.x); o[1]=f2b(a.y); o[2]=f2b(a.z); o[3]=f2b(a.w);
  o[4]=f2b(b.x); o[5]=f2b(b.y); o[6]=f2b(b.z); o[7]=f2b(b.w);
  *(bf16x8*)(out + i) = o;
}

// ---------------- W [K][N] fp32 -> Wt rows [row0+n][k] bf16 ----------------
__global__ __launch_bounds__(256) void k_transpose_w(const float* __restrict__ W,
                                                     short* __restrict__ Wt, int row0) {
  __shared__ short t[64][72];
  int tid = threadIdx.x;
  int n0 = blockIdx.x * 64, k0 = blockIdx.y * 64;
  #pragma unroll
  for (int i = 0; i < 4; i++) {
    int id = tid + 256 * i;
    int r = id >> 4;        // k row within tile
    int c = id & 15;        // float4 chunk along n
    float4 v = *(const float4*)(W + (size_t)(k0 + r) * DM + n0 + c * 4);
    t[c*4+0][r] = f2b(v.x);
    t[c*4+1][r] = f2b(v.y);
    t[c*4+2][r] = f2b(v.z);
    t[c*4+3][r] = f2b(v.w);
  }
  __syncthreads();
  #pragma unroll
  for (int i = 0; i < 2; i++) {
    int id = tid + 256 * i;
    int r = id >> 3;        // n row
    int c = id & 7;         // 8-elem chunk along k
    bf16x8 o = *(const bf16x8*)&t[r][c * 8];
    *(bf16x8*)(Wt + (size_t)(row0 + n0 + r) * DM + k0 + c * 8) = o;
  }
}

// ---------------- V (cols of Qkv) -> Vt [BB*NH][64][TT] bf16 ----------------
__global__ __launch_bounds__(256) void k_transpose_v(const short* __restrict__ V,
                                                     short* __restrict__ Vt) {
  __shared__ short t[64][72];
  int tid = threadIdx.x;
  int bh = blockIdx.y;
  int b = bh >> 4, h = bh & 15;
  int t0 = blockIdx.x * 64;
  #pragma unroll
  for (int i = 0; i < 2; i++) {
    int id = tid + 256 * i;
    int r = id >> 3;        // t row
    int c = id & 7;         // 8-bf16 chunk along d
    bf16x8 v = *(const bf16x8*)(V + (size_t)(b * TT + t0 + r) * DQKV + h * 64 + c * 8);
    #pragma unroll
    for (int e = 0; e < 8; e++) t[c * 8 + e][r] = v[e];
  }
  __syncthreads();
  #pragma unroll
  for (int i = 0; i < 2; i++) {
    int id = tid + 256 * i;
    int r = id >> 3;        // d row
    int c = id & 7;         // t chunk
    bf16x8 o = *(const bf16x8*)&t[r][c * 8];
    *(bf16x8*)(Vt + (size_t)(bh * 64 + r) * TT + t0 + c * 8) = o;
  }
}

// ---------------- GEMM NT (m97 structure): C[M][N] = A[M][K] * Bt[N][K]^T ----------------
template<int OUT_BF16, int BN>
__global__ __launch_bounds__(256) void k_gemm_lds(const short* __restrict__ A,
                                                  const short* __restrict__ Bt,
                                                  void* __restrict__ C,
                                                  int M, int N, int K) {
  __shared__ short As[128 * 64];
  __shared__ short Bs[BN * 64];
  constexpr int NI = BN / 32;               // 16-wide n-frags per wave
  const int tid = threadIdx.x;
  const int lane = tid & 63, w = tid >> 6;
  const int wm = w >> 1, wn = w & 1;        // 2x2 wave grid
  const int l15 = lane & 15, g = lane >> 4;
  const int m0 = blockIdx.y * 128, n0 = blockIdx.x * BN;
  const int srow = lane >> 3;               // 0..7 within 8-row segment
  const int scol = (lane & 7) * 8;          // shorts (16B chunks)
  f32x4 acc[4][NI] = {};
  for (int k0 = 0; k0 < K; k0 += 64) {
    #pragma unroll
    for (int i = 0; i < 4; i++) {
      int rbase = w * 32 + i * 8;
      __builtin_amdgcn_global_load_lds(
        (const __attribute__((address_space(1))) void*)(A + (size_t)(m0 + rbase + srow) * K + k0 + scol),
        (__attribute__((address_space(3))) void*)&As[rbase * 64],
        16, 0, 0);
    }
    #pragma unroll
    for (int i = 0; i < BN / 32; i++) {
      int rbase = w * (BN / 4) + i * 8;
      __builtin_amdgcn_global_load_lds(
        (const __attribute__((address_space(1))) void*)(Bt + (size_t)(n0 + rbase + srow) * K + k0 + scol),
        (__attribute__((address_space(3))) void*)&Bs[rbase * 64],
        16, 0, 0);
    }
    __syncthreads();
    #pragma unroll
    for (int kk = 0; kk < 64; kk += 32) {
      bf16x8 af[4], bfr[NI];
      #pragma unroll
      for (int mi = 0; mi < 4; mi++)
        af[mi] = *(const bf16x8*)&As[(wm * 64 + mi * 16 + l15) * 64 + kk + 8 * g];
      #pragma unroll
      for (int ni = 0; ni < NI; ni++)
        bfr[ni] = *(const bf16x8*)&Bs[(wn * (BN / 2) + ni * 16 + l15) * 64 + kk + 8 * g];
      #pragma unroll
      for (int mi = 0; mi < 4; mi++)
        #pragma unroll
        for (int ni = 0; ni < NI; ni++)
          acc[mi][ni] = __builtin_amdgcn_mfma_f32_16x16x32_bf16(af[mi], bfr[ni], acc[mi][ni], 0, 0, 0);
    }
    __syncthreads();
  }
  #pragma unroll
  for (int mi = 0; mi < 4; mi++) {
    #pragma unroll
    for (int ni = 0; ni < NI; ni++) {
      #pragma unroll
      for (int j = 0; j < 4; j++) {
        int row = m0 + wm * 64 + mi * 16 + g * 4 + j;
        int col = n0 + wn * (BN / 2) + ni * 16 + l15;
        float v = acc[mi][ni][j];
        if (OUT_BF16) ((short*)C)[(size_t)row * N + col] = f2b(v);
        else          ((float*)C)[(size_t)row * N + col] = v;
      }
    }
  }
}

// ---------------- flash attention: barrier-free, per-wave tasks, L2-direct K/V ----------------
// 1024 blocks x 4 waves; each WAVE owns one 16-row q-tile and is fully
// independent (no __syncthreads). K/V fragments read directly from L2
// (per-head K/V = 256KB, XCD-L2-resident via chunked remap; m169 lesson:
// LDS staging of L2-fit data is pure overhead). K frags rotate-loaded one
// tile ahead; V issued early, consumed after softmax. P round-trips through
// wave-private LDS (lgkm wait only).
__global__ __launch_bounds__(256) void k_attn(const short* __restrict__ Qkv,
                                              const short* __restrict__ Vt,
                                              short* __restrict__ Y) {
  __shared__ short Ps[4][16 * 64];
  const int tid = threadIdx.x;
  const int lane = tid & 63, w = tid >> 6;
  const int l15 = lane & 15, g = lane >> 4;
  // XCD-chunked remap: 128 consecutive logical ids per XCD -> 4 bh per XCD.
  const int l = ((blockIdx.x & 7) << 7) | (blockIdx.x >> 3);
  const int bh = l >> 5, m = l & 31;
  const int b = bh >> 4, h = bh & 15;
  const int qt = 127 - (m * 4 + w);        // big tasks first; uniform within block
  const int q0 = qt * 16;                  // q-row base within (b,h)
  const int nkt = (qt >> 2) + 1;           // 64-key tiles to process
  const short* Qb = Qkv;
  const short* Kb = Qkv + DM;
  short* PsW = Ps[w];
  const int rsw = (l15 & 7) << 3;          // P read-side XOR (shorts)

  // Q fragments: rows q0 + l15, k = head dim (2 chunks of 32)
  bf16x8 aq[2];
  #pragma unroll
  for (int kc = 0; kc < 2; kc++)
    aq[kc] = *(const bf16x8*)(Qb + (size_t)(b * TT + q0 + l15) * DQKV + h * 64 + kc * 32 + 8 * g);

  f32x4 accO[4] = {};
  float mrow[4], lrow[4];
  #pragma unroll
  for (int j = 0; j < 4; j++) { mrow[j] = -1e30f; lrow[j] = 0.f; }

  // preload K tile 0 fragments (B-layout: row=key, 8 contiguous k-elems)
  bf16x8 kf[8];
  #pragma unroll
  for (int n = 0; n < 4; n++)
    #pragma unroll
    for (int kc = 0; kc < 2; kc++)
      kf[n * 2 + kc] = *(const bf16x8*)(Kb + (size_t)(b * TT + n * 16 + l15) * DQKV + h * 64 + kc * 32 + 8 * g);

  for (int kt = 0; kt < nkt; kt++) {
    // V fragments for this tile, issued early (consumed after softmax)
    bf16x8 vf[8];
    #pragma unroll
    for (int n2 = 0; n2 < 4; n2++)
      #pragma unroll
      for (int kc = 0; kc < 2; kc++)
        vf[n2 * 2 + kc] = *(const bf16x8*)(Vt + (size_t)(bh * 64 + n2 * 16 + l15) * TT + kt * 64 + kc * 32 + 8 * g);

    // S = Q K^T  (16 q x 64 keys)
    f32x4 accS[4] = {};
    __builtin_amdgcn_s_setprio(1);
    #pragma unroll
    for (int n = 0; n < 4; n++)
      #pragma unroll
      for (int kc = 0; kc < 2; kc++)
        accS[n] = __builtin_amdgcn_mfma_f32_16x16x32_bf16(aq[kc], kf[n * 2 + kc], accS[n], 0, 0, 0);
    __builtin_amdgcn_s_setprio(0);

    // rotate: K fragments for next tile (softmax+PV covers L2 latency)
    if (kt + 1 < nkt) {
      #pragma unroll
      for (int n = 0; n < 4; n++)
        #pragma unroll
        for (int kc = 0; kc < 2; kc++)
          kf[n * 2 + kc] = *(const bf16x8*)(Kb + (size_t)(b * TT + (kt + 1) * 64 + n * 16 + l15) * DQKV + h * 64 + kc * 32 + 8 * g);
    }

    // scale + (diag-only) causal mask; per-row (j) online softmax, p in accS
    float tmax[4];
    #pragma unroll
    for (int j = 0; j < 4; j++) tmax[j] = -1e30f;
    const int qbase = q0 + g * 4;
    if (kt == (qt >> 2)) {   // diagonal tile (wave-uniform branch)
      #pragma unroll
      for (int n = 0; n < 4; n++) {
        int key = kt * 64 + n * 16 + l15;
        #pragma unroll
        for (int j = 0; j < 4; j++) {
          float s = accS[n][j] * 0.125f;
          if (key > qbase + j) s = -1e30f;
          accS[n][j] = s;
          tmax[j] = fmaxf(tmax[j], s);
        }
      }
    } else {
      #pragma unroll
      for (int n = 0; n < 4; n++)
        #pragma unroll
        for (int j = 0; j < 4; j++) {
          float s = accS[n][j] * 0.125f;
          accS[n][j] = s;
          tmax[j] = fmaxf(tmax[j], s);
        }
    }
    #pragma unroll
    for (int j = 0; j < 4; j++) {
      #pragma unroll
      for (int off = 1; off < 16; off <<= 1)
        tmax[j] = fmaxf(tmax[j], __shfl_xor(tmax[j], off));
    }
    float alpha[4], rsum[4];
    #pragma unroll
    for (int j = 0; j < 4; j++) {
      float mnew = fmaxf(mrow[j], tmax[j]);
      alpha[j] = __expf(mrow[j] - mnew);
      mrow[j] = mnew;
      float s0 = 0.f;
      #pragma unroll
      for (int n = 0; n < 4; n++) {
        float e = __expf(accS[n][j] - mnew);
        accS[n][j] = e;
        s0 += e;
      }
      rsum[j] = s0;
    }
    #pragma unroll
    for (int j = 0; j < 4; j++) {
      #pragma unroll
      for (int off = 1; off < 16; off <<= 1)
        rsum[j] += __shfl_xor(rsum[j], off);
      lrow[j] = lrow[j] * alpha[j] + rsum[j];
    }
    #pragma unroll
    for (int n2 = 0; n2 < 4; n2++)
      #pragma unroll
      for (int j = 0; j < 4; j++)
        accO[n2][j] *= alpha[j];
    // P (C-layout) -> wave-private LDS (swizzled) -> A-layout fragments
    #pragma unroll
    for (int n = 0; n < 4; n++)
      #pragma unroll
      for (int j = 0; j < 4; j++) {
        int ql = g * 4 + j;
        PsW[ql * 64 + ((n * 16 + l15) ^ ((ql & 7) << 3))] = f2b(accS[n][j]);
      }
    __builtin_amdgcn_s_setprio(1);
    #pragma unroll
    for (int kc = 0; kc < 2; kc++) {
      bf16x8 pa = *(const bf16x8*)&PsW[l15 * 64 + ((kc * 32 + 8 * g) ^ rsw)];
      #pragma unroll
      for (int n2 = 0; n2 < 4; n2++)
        accO[n2] = __builtin_amdgcn_mfma_f32_16x16x32_bf16(pa, vf[n2 * 2 + kc], accO[n2], 0, 0, 0);
    }
    __builtin_amdgcn_s_setprio(0);
  }
  // normalize + write Y (bf16, head h columns)
  const int orow = b * TT + q0;
  #pragma unroll
  for (int n2 = 0; n2 < 4; n2++) {
    #pragma unroll
    for (int j = 0; j < 4; j++) {
      float v = accO[n2][j] / lrow[j];
      Y[(size_t)(orow + g * 4 + j) * DM + h * 64 + n2 * 16 + l15] = f2b(v);
    }
  }
}

extern "C" void kernel_launch(void* const* d_in, const int* in_sizes, int n_in,
                              void* d_out, int out_size, void* d_ws, size_t ws_size,
                              hipStream_t stream) {
  const float* x  = (const float*)d_in[0];
  const float* Wq = (const float*)d_in[1];
  const float* Wk = (const float*)d_in[2];
  const float* Wv = (const float*)d_in[3];
  const float* Wo = (const float*)d_in[4];
  float* out = (float*)d_out;

  char* ws = (char*)d_ws;
  size_t off = 0;
  auto alloc = [&](size_t bytes) {
    char* p = ws + off;
    off += (bytes + 255) & ~(size_t)255;
    return p;
  };
  short* xb    = (short*)alloc((size_t)NTOK * DM * 2);    // also reused as Y
  short* WqkvT = (short*)alloc((size_t)DQKV * DM * 2);    // [3072][1024]
  short* WoT   = (short*)alloc((size_t)DM * DM * 2);
  short* Qkv   = (short*)alloc((size_t)NTOK * DQKV * 2);  // [4096][3072]
  short* Vt    = (short*)alloc((size_t)NTOK * DM * 2);    // [32][64][2048]
  short* Yb    = xb;   // x dead after QKV GEMM; reuse region for Y
  if (off > ws_size) return;   // workspace too small -> loud failure

  k_convert<<<(NTOK * DM) / (256 * 8), 256, 0, stream>>>(x, xb, NTOK * DM);
  dim3 tw(DM / 64, DM / 64);
  k_transpose_w<<<tw, 256, 0, stream>>>(Wq, WqkvT, 0);
  k_transpose_w<<<tw, 256, 0, stream>>>(Wk, WqkvT, 1024);
  k_transpose_w<<<tw, 256, 0, stream>>>(Wv, WqkvT, 2048);
  k_transpose_w<<<tw, 256, 0, stream>>>(Wo, WoT, 0);

  // fused QKV GEMM: [4096][1024] x [3072][1024]^T -> [4096][3072] bf16
  k_gemm_lds<1, 128><<<dim3(DQKV / 128, NTOK / 128), 256, 0, stream>>>(xb, WqkvT, Qkv, NTOK, DQKV, DM);

  k_transpose_v<<<dim3(TT / 64, BB * NH), 256, 0, stream>>>(Qkv + 2048, Vt);
  k_attn<<<dim3(1024), 256, 0, stream>>>(Qkv, Vt, Yb);

  // out projection: [4096][1024] x [1024][1024]^T -> fp32 out (128x64 tiles, 512 blocks)
  k_gemm_lds<0, 64><<<dim3(DM / 64, NTOK / 128), 256, 0, stream>>>(Yb, WoT, out, NTOK, DM, DM);
}

// Round 5
// 154.460 us; speedup vs baseline: 1.7034x; 1.7034x over previous
//
#include <hip/hip_runtime.h>

#define DM 1024
#define NH 16
#define TT 2048
#define BB 2
#define NTOK (BB*TT)
#define DQKV 3072

typedef __attribute__((ext_vector_type(8))) short bf16x8;   // 8 bf16 (4 VGPRs)
typedef __attribute__((ext_vector_type(4))) float f32x4;    // MFMA C/D
typedef __attribute__((ext_vector_type(4))) int  int4v;     // 16B chunk

static __device__ __forceinline__ short f2b(float f) {
  union { float f; unsigned u; } v; v.f = f;
  unsigned r = v.u + 0x7FFFu + ((v.u >> 16) & 1u);   // RNE fp32->bf16
  return (short)(r >> 16);
}

// ---------------- fp32 -> bf16 convert (x) ----------------
__global__ __launch_bounds__(256) void k_convert(const float* __restrict__ in,
                                                 short* __restrict__ out, int n) {
  int i = (blockIdx.x * 256 + threadIdx.x) * 8;
  if (i >= n) return;
  float4 a = *(const float4*)(in + i);
  float4 b = *(const float4*)(in + i + 4);
  bf16x8 o;
  o[0]=f2b(a.x); o[1]=f2b(a.y); o[2]=f2b(a.z); o[3]=f2b(a.w);
  o[4]=f2b(b.x); o[5]=f2b(b.y); o[6]=f2b(b.z); o[7]=f2b(b.w);
  *(bf16x8*)(out + i) = o;
}

// ---------------- W [K][N] fp32 -> Wt rows [row0+n][k] bf16 ----------------
__global__ __launch_bounds__(256) void k_transpose_w(const float* __restrict__ W,
                                                     short* __restrict__ Wt, int row0) {
  __shared__ short t[64][72];
  int tid = threadIdx.x;
  int n0 = blockIdx.x * 64, k0 = blockIdx.y * 64;
  #pragma unroll
  for (int i = 0; i < 4; i++) {
    int id = tid + 256 * i;
    int r = id >> 4;        // k row within tile
    int c = id & 15;        // float4 chunk along n
    float4 v = *(const float4*)(W + (size_t)(k0 + r) * DM + n0 + c * 4);
    t[c*4+0][r] = f2b(v.x);
    t[c*4+1][r] = f2b(v.y);
    t[c*4+2][r] = f2b(v.z);
    t[c*4+3][r] = f2b(v.w);
  }
  __syncthreads();
  #pragma unroll
  for (int i = 0; i < 2; i++) {
    int id = tid + 256 * i;
    int r = id >> 3;        // n row
    int c = id & 7;         // 8-elem chunk along k
    bf16x8 o = *(const bf16x8*)&t[r][c * 8];
    *(bf16x8*)(Wt + (size_t)(row0 + n0 + r) * DM + k0 + c * 8) = o;
  }
}

// ---------------- V (cols of Qkv) -> Vt [BB*NH][64][TT] bf16 ----------------
__global__ __launch_bounds__(256) void k_transpose_v(const short* __restrict__ V,
                                                     short* __restrict__ Vt) {
  __shared__ short t[64][72];
  int tid = threadIdx.x;
  int bh = blockIdx.y;
  int b = bh >> 4, h = bh & 15;
  int t0 = blockIdx.x * 64;
  #pragma unroll
  for (int i = 0; i < 2; i++) {
    int id = tid + 256 * i;
    int r = id >> 3;        // t row
    int c = id & 7;         // 8-bf16 chunk along d
    bf16x8 v = *(const bf16x8*)(V + (size_t)(b * TT + t0 + r) * DQKV + h * 64 + c * 8);
    #pragma unroll
    for (int e = 0; e < 8; e++) t[c * 8 + e][r] = v[e];
  }
  __syncthreads();
  #pragma unroll
  for (int i = 0; i < 2; i++) {
    int id = tid + 256 * i;
    int r = id >> 3;        // d row
    int c = id & 7;         // t chunk
    bf16x8 o = *(const bf16x8*)&t[r][c * 8];
    *(bf16x8*)(Vt + (size_t)(bh * 64 + r) * TT + t0 + c * 8) = o;
  }
}

// ---------------- GEMM NT (m97 structure): C[M][N] = A[M][K] * Bt[N][K]^T ----------------
// qcols/qscale: bf16 outputs in cols [0,qcols) are scaled by qscale (used to
// pre-fold the attention softmax scale*log2e into Q at zero marginal cost).
template<int OUT_BF16, int BN>
__global__ __launch_bounds__(256) void k_gemm_lds(const short* __restrict__ A,
                                                  const short* __restrict__ Bt,
                                                  void* __restrict__ C,
                                                  int M, int N, int K,
                                                  int qcols, float qscale) {
  __shared__ short As[128 * 64];
  __shared__ short Bs[BN * 64];
  constexpr int NI = BN / 32;               // 16-wide n-frags per wave
  const int tid = threadIdx.x;
  const int lane = tid & 63, w = tid >> 6;
  const int wm = w >> 1, wn = w & 1;        // 2x2 wave grid
  const int l15 = lane & 15, g = lane >> 4;
  const int m0 = blockIdx.y * 128, n0 = blockIdx.x * BN;
  const int srow = lane >> 3;               // 0..7 within 8-row segment
  const int scol = (lane & 7) * 8;          // shorts (16B chunks)
  f32x4 acc[4][NI] = {};
  for (int k0 = 0; k0 < K; k0 += 64) {
    #pragma unroll
    for (int i = 0; i < 4; i++) {
      int rbase = w * 32 + i * 8;
      __builtin_amdgcn_global_load_lds(
        (const __attribute__((address_space(1))) void*)(A + (size_t)(m0 + rbase + srow) * K + k0 + scol),
        (__attribute__((address_space(3))) void*)&As[rbase * 64],
        16, 0, 0);
    }
    #pragma unroll
    for (int i = 0; i < BN / 32; i++) {
      int rbase = w * (BN / 4) + i * 8;
      __builtin_amdgcn_global_load_lds(
        (const __attribute__((address_space(1))) void*)(Bt + (size_t)(n0 + rbase + srow) * K + k0 + scol),
        (__attribute__((address_space(3))) void*)&Bs[rbase * 64],
        16, 0, 0);
    }
    __syncthreads();
    #pragma unroll
    for (int kk = 0; kk < 64; kk += 32) {
      bf16x8 af[4], bfr[NI];
      #pragma unroll
      for (int mi = 0; mi < 4; mi++)
        af[mi] = *(const bf16x8*)&As[(wm * 64 + mi * 16 + l15) * 64 + kk + 8 * g];
      #pragma unroll
      for (int ni = 0; ni < NI; ni++)
        bfr[ni] = *(const bf16x8*)&Bs[(wn * (BN / 2) + ni * 16 + l15) * 64 + kk + 8 * g];
      #pragma unroll
      for (int mi = 0; mi < 4; mi++)
        #pragma unroll
        for (int ni = 0; ni < NI; ni++)
          acc[mi][ni] = __builtin_amdgcn_mfma_f32_16x16x32_bf16(af[mi], bfr[ni], acc[mi][ni], 0, 0, 0);
    }
    __syncthreads();
  }
  #pragma unroll
  for (int mi = 0; mi < 4; mi++) {
    #pragma unroll
    for (int ni = 0; ni < NI; ni++) {
      #pragma unroll
      for (int j = 0; j < 4; j++) {
        int row = m0 + wm * 64 + mi * 16 + g * 4 + j;
        int col = n0 + wn * (BN / 2) + ni * 16 + l15;
        float v = acc[mi][ni][j];
        if (OUT_BF16) {
          if (col < qcols) v *= qscale;     // wave-uniform (block cols span <128)
          ((short*)C)[(size_t)row * N + col] = f2b(v);
        } else {
          ((float*)C)[(size_t)row * N + col] = v;
        }
      }
    }
  }
}

// ---------------- flash attention, paired q-tiles (r2 structure) ----------------
// grid: (16, NH, BB); block j handles q-tiles j and 31-j (33 k-tiles, uniform).
// 4 waves x 16 q-rows; 64-key tiles; double-buffered K/V, T14 async-STAGE split.
// Softmax in log2 domain (Q pre-scaled by 0.125*log2e in GEMM epilogue):
// T13 defer-max (THR=8), lane-partial row sums (one reduce at end).
__global__ __launch_bounds__(256) void k_attn(const short* __restrict__ Qkv,
                                              const short* __restrict__ Vt,
                                              short* __restrict__ Y) {
  __shared__ short Ks[2][64 * 72];
  __shared__ short Vs[2][64 * 72];
  __shared__ short Ps[4 * 16 * 72];
  const int tid = threadIdx.x;
  const int lane = tid & 63, w = tid >> 6;
  const int l15 = lane & 15, g = lane >> 4;
  const int pair = blockIdx.x;
  const int h = blockIdx.y, b = blockIdx.z;
  const int bh = b * NH + h;
  const short* Qb = Qkv;                 // cols [0,1024), pre-scaled
  const short* Kb = Qkv + DM;            // cols [1024,2048)

  int4v rK[2], rV[2];

  #pragma unroll 1
  for (int sel = 0; sel < 2; sel++) {
    const int qi = sel ? (31 - pair) : pair;
    const int q0 = qi * 64;
    const int nkt = qi + 1;

    // Q fragments for this q-tile
    bf16x8 aq[2];
    #pragma unroll
    for (int kc = 0; kc < 2; kc++)
      aq[kc] = *(const bf16x8*)(Qb + (size_t)(b * TT + q0 + w * 16 + l15) * DQKV + h * 64 + kc * 32 + 8 * g);

    f32x4 accO[4] = {};
    float m2[4], lp[4];                  // running log2-max (row-uniform), lane-PARTIAL sums
    #pragma unroll
    for (int j = 0; j < 4; j++) { m2[j] = -1e30f; lp[j] = 0.f; }

    // prologue: stage tile 0 into buf 0
    #pragma unroll
    for (int i = 0; i < 2; i++) {
      int id = tid + 256 * i, r = id >> 3, c = id & 7;
      rK[i] = *(const int4v*)(Kb + (size_t)(b * TT + r) * DQKV + h * 64 + c * 8);
      rV[i] = *(const int4v*)(Vt + (size_t)(bh * 64 + r) * TT + c * 8);
    }
    #pragma unroll
    for (int i = 0; i < 2; i++) {
      int id = tid + 256 * i, r = id >> 3, c = id & 7;
      *(int4v*)&Ks[0][r * 72 + c * 8] = rK[i];
      *(int4v*)&Vs[0][r * 72 + c * 8] = rV[i];
    }
    __syncthreads();

    for (int kt = 0; kt < nkt; kt++) {
      const int cur = kt & 1;
      // T14: issue next tile's global loads before compute
      if (kt + 1 < nkt) {
        #pragma unroll
        for (int i = 0; i < 2; i++) {
          int id = tid + 256 * i, r = id >> 3, c = id & 7;
          rK[i] = *(const int4v*)(Kb + (size_t)(b * TT + (kt + 1) * 64 + r) * DQKV + h * 64 + c * 8);
          rV[i] = *(const int4v*)(Vt + (size_t)(bh * 64 + r) * TT + (kt + 1) * 64 + c * 8);
        }
      }
      const short* Ksb = Ks[cur];
      const short* Vsb = Vs[cur];

      // S(log2 units) = Qs K^T  (16 q x 64 keys)
      f32x4 accS[4] = {};
      __builtin_amdgcn_s_setprio(1);
      #pragma unroll
      for (int n = 0; n < 4; n++) {
        #pragma unroll
        for (int kc = 0; kc < 2; kc++) {
          bf16x8 bk = *(const bf16x8*)&Ksb[(n * 16 + l15) * 72 + kc * 32 + 8 * g];
          accS[n] = __builtin_amdgcn_mfma_f32_16x16x32_bf16(aq[kc], bk, accS[n], 0, 0, 0);
        }
      }
      __builtin_amdgcn_s_setprio(0);

      // causal mask (diag tile only) + lane-partial row maxima
      float tmaxp[4];
      #pragma unroll
      for (int j = 0; j < 4; j++) tmaxp[j] = -1e30f;
      const int qbase = q0 + w * 16 + g * 4;
      if (kt == qi) {    // diagonal tile (wave-uniform branch)
        #pragma unroll
        for (int n = 0; n < 4; n++) {
          int key = kt * 64 + n * 16 + l15;
          #pragma unroll
          for (int j = 0; j < 4; j++) {
            float s = accS[n][j];
            if (key > qbase + j) s = -1e30f;
            accS[n][j] = s;
            tmaxp[j] = fmaxf(tmaxp[j], s);
          }
        }
      } else {
        #pragma unroll
        for (int n = 0; n < 4; n++)
          #pragma unroll
          for (int j = 0; j < 4; j++)
            tmaxp[j] = fmaxf(tmaxp[j], accS[n][j]);
      }

      // T13 defer-max: rescale only when some row's partial max exceeds m2+8
      float dmax = fmaxf(fmaxf(tmaxp[0] - m2[0], tmaxp[1] - m2[1]),
                         fmaxf(tmaxp[2] - m2[2], tmaxp[3] - m2[3]));
      if (!__all(dmax <= 8.0f)) {
        #pragma unroll
        for (int j = 0; j < 4; j++) {
          float t = tmaxp[j];
          #pragma unroll
          for (int off = 1; off < 16; off <<= 1)
            t = fmaxf(t, __shfl_xor(t, off));
          float mnew = fmaxf(m2[j], t);
          float al = exp2f(m2[j] - mnew);
          m2[j] = mnew;
          lp[j] *= al;
          #pragma unroll
          for (int n2 = 0; n2 < 4; n2++) accO[n2][j] *= al;
        }
      }

      // p = 2^(s - m2) (bounded by 2^8); partial sums; store truncated bf16
      #pragma unroll
      for (int n = 0; n < 4; n++) {
        #pragma unroll
        for (int j = 0; j < 4; j++) {
          float e = exp2f(accS[n][j] - m2[j]);
          lp[j] += e;
          union { float f; unsigned u; } cv; cv.f = e;
          Ps[(w * 16 + g * 4 + j) * 72 + n * 16 + l15] = (short)(cv.u >> 16); // trunc
        }
      }

      __builtin_amdgcn_s_setprio(1);
      #pragma unroll
      for (int kc = 0; kc < 2; kc++) {
        bf16x8 pa = *(const bf16x8*)&Ps[(w * 16 + l15) * 72 + kc * 32 + 8 * g];
        #pragma unroll
        for (int n2 = 0; n2 < 4; n2++) {
          bf16x8 vb = *(const bf16x8*)&Vsb[(n2 * 16 + l15) * 72 + kc * 32 + 8 * g];
          accO[n2] = __builtin_amdgcn_mfma_f32_16x16x32_bf16(pa, vb, accO[n2], 0, 0, 0);
        }
      }
      __builtin_amdgcn_s_setprio(0);

      // T14: commit next tile into the other buffer after compute
      if (kt + 1 < nkt) {
        #pragma unroll
        for (int i = 0; i < 2; i++) {
          int id = tid + 256 * i, r = id >> 3, c = id & 7;
          *(int4v*)&Ks[cur ^ 1][r * 72 + c * 8] = rK[i];
          *(int4v*)&Vs[cur ^ 1][r * 72 + c * 8] = rV[i];
        }
      }
      __syncthreads();
    }
    // reduce lane-partial sums once, normalize, write Y
    float lr[4];
    #pragma unroll
    for (int j = 0; j < 4; j++) {
      float s = lp[j];
      #pragma unroll
      for (int off = 1; off < 16; off <<= 1)
        s += __shfl_xor(s, off);
      lr[j] = s;
    }
    const int orow = b * TT + q0 + w * 16;
    #pragma unroll
    for (int n2 = 0; n2 < 4; n2++) {
      #pragma unroll
      for (int j = 0; j < 4; j++) {
        float v = accO[n2][j] / lr[j];
        Y[(size_t)(orow + g * 4 + j) * DM + h * 64 + n2 * 16 + l15] = f2b(v);
      }
    }
  }
}

extern "C" void kernel_launch(void* const* d_in, const int* in_sizes, int n_in,
                              void* d_out, int out_size, void* d_ws, size_t ws_size,
                              hipStream_t stream) {
  const float* x  = (const float*)d_in[0];
  const float* Wq = (const float*)d_in[1];
  const float* Wk = (const float*)d_in[2];
  const float* Wv = (const float*)d_in[3];
  const float* Wo = (const float*)d_in[4];
  float* out = (float*)d_out;

  char* ws = (char*)d_ws;
  size_t off = 0;
  auto alloc = [&](size_t bytes) {
    char* p = ws + off;
    off += (bytes + 255) & ~(size_t)255;
    return p;
  };
  short* xb    = (short*)alloc((size_t)NTOK * DM * 2);    // also reused as Y
  short* WqkvT = (short*)alloc((size_t)DQKV * DM * 2);    // [3072][1024]
  short* WoT   = (short*)alloc((size_t)DM * DM * 2);
  short* Qkv   = (short*)alloc((size_t)NTOK * DQKV * 2);  // [4096][3072]
  short* Vt    = (short*)alloc((size_t)NTOK * DM * 2);    // [32][64][2048]
  short* Yb    = xb;   // x dead after QKV GEMM; reuse region for Y
  if (off > ws_size) return;   // workspace too small -> loud failure

  k_convert<<<(NTOK * DM) / (256 * 8), 256, 0, stream>>>(x, xb, NTOK * DM);
  dim3 tw(DM / 64, DM / 64);
  k_transpose_w<<<tw, 256, 0, stream>>>(Wq, WqkvT, 0);
  k_transpose_w<<<tw, 256, 0, stream>>>(Wk, WqkvT, 1024);
  k_transpose_w<<<tw, 256, 0, stream>>>(Wv, WqkvT, 2048);
  k_transpose_w<<<tw, 256, 0, stream>>>(Wo, WoT, 0);

  // fused QKV GEMM; Q cols pre-scaled by 0.125*log2e (softmax in log2 domain)
  const float QSC = 0.125f * 1.44269504088896f;
  k_gemm_lds<1, 128><<<dim3(DQKV / 128, NTOK / 128), 256, 0, stream>>>(xb, WqkvT, Qkv, NTOK, DQKV, DM, DM, QSC);

  k_transpose_v<<<dim3(TT / 64, BB * NH), 256, 0, stream>>>(Qkv + 2048, Vt);
  k_attn<<<dim3(16, NH, BB), 256, 0, stream>>>(Qkv, Vt, Yb);

  // out projection: [4096][1024] x [1024][1024]^T -> fp32 out (128x64 tiles, 512 blocks)
  k_gemm_lds<0, 64><<<dim3(DM / 64, NTOK / 128), 256, 0, stream>>>(Yb, WoT, out, NTOK, DM, DM, 0, 1.0f);
}